// Round 1
// baseline (1005.116 us; speedup 1.0000x reference)
//
#include <hip/hip_runtime.h>
#include <stdint.h>

// ---------- types ----------
typedef unsigned short ushort_t;
typedef __attribute__((ext_vector_type(4))) float  floatx4;
typedef __attribute__((ext_vector_type(8))) short  shortx8;   // 8 bf16 (4 VGPRs)

// ---------- bf16 helpers (raw ushort representation) ----------
__device__ __forceinline__ float bf2f(ushort_t u) {
  union { float f; unsigned int i; } x; x.i = ((unsigned int)u) << 16; return x.f;
}
__device__ __forceinline__ ushort_t f2bf(float f) {
  union { float f; unsigned int i; } x; x.f = f;
  unsigned int r = x.i + 0x7fffu + ((x.i >> 16) & 1u);   // RNE
  return (ushort_t)(r >> 16);
}

// ---------- async global->LDS, 16B per lane ----------
__device__ __forceinline__ void gl_lds16(const ushort_t* g, ushort_t* l) {
  __builtin_amdgcn_global_load_lds(
      (const __attribute__((address_space(1))) void*)g,
      (__attribute__((address_space(3))) void*)l, 16, 0, 0);
}

// ---------- fp32 -> bf16 cast, 8 elems/thread ----------
__global__ __launch_bounds__(256) void cast_f32_bf16(const float* __restrict__ in,
                                                     ushort_t* __restrict__ out, long n) {
  long i = ((long)blockIdx.x * 256 + threadIdx.x) * 8;
  if (i + 8 > n) return;
  floatx4 a = *(const floatx4*)(in + i);
  floatx4 b = *(const floatx4*)(in + i + 4);
  union { shortx8 v; ushort_t h[8]; } u;
  u.h[0] = f2bf(a.x); u.h[1] = f2bf(a.y); u.h[2] = f2bf(a.z); u.h[3] = f2bf(a.w);
  u.h[4] = f2bf(b.x); u.h[5] = f2bf(b.y); u.h[6] = f2bf(b.z); u.h[7] = f2bf(b.w);
  *(shortx8*)(out + i) = u.v;
}

// ---------- m97-style GEMM: C[M][1024] = A[M][1024] * B^T + bias ----------
// A: bf16 [M][K=1024] row-major, B: bf16 [N=1024][K=1024] row-major (weights!)
// grid: (M/128, 1024/128), block 256 (4 waves, 2x2 of 64x64)
template <bool BF16OUT>
__global__ __launch_bounds__(256, 2) void gemm_bt(const ushort_t* __restrict__ A,
                                                  const ushort_t* __restrict__ B,
                                                  const float* __restrict__ bias,
                                                  void* __restrict__ Cv) {
  constexpr int K = 1024;
  constexpr int N = 1024;
  __shared__ ushort_t As[128 * 32];
  __shared__ ushort_t Bs[128 * 32];

  const int t    = threadIdx.x;
  const int lane = t & 63;
  const int w    = t >> 6;
  const int wm   = w >> 1, wn = w & 1;
  const size_t row0 = (size_t)blockIdx.x * 128;
  const int    col0 = blockIdx.y * 128;

  // staging addresses: thread t loads 8 bf16 (16B) at tile row t>>2, col (t&3)*8
  const int sr = t >> 2;
  const int sc = (t & 3) * 8;
  const ushort_t* Ag = A + (row0 + sr) * K + sc;
  const ushort_t* Bg = B + (size_t)(col0 + sr) * K + sc;
  ushort_t* Al = As + t * 8;
  ushort_t* Bl = Bs + t * 8;

  floatx4 acc[4][4] = {};

  const int kg = (lane >> 4) * 8;       // k-group 0,8,16,24
  const int fr = lane & 15;             // fragment row/col within 16

  for (int k0 = 0; k0 < K; k0 += 32) {
    __syncthreads();
    gl_lds16(Ag + k0, Al);
    gl_lds16(Ag + 64 * K + k0, Al + 2048);
    gl_lds16(Bg + k0, Bl);
    gl_lds16(Bg + 64 * K + k0, Bl + 2048);
    __syncthreads();

    shortx8 af[4], bfr[4];
#pragma unroll
    for (int i = 0; i < 4; ++i) {
      af[i]  = *(const shortx8*)&As[(wm * 64 + i * 16 + fr) * 32 + kg];
      bfr[i] = *(const shortx8*)&Bs[(wn * 64 + i * 16 + fr) * 32 + kg];
    }
#pragma unroll
    for (int mt = 0; mt < 4; ++mt)
#pragma unroll
      for (int nt = 0; nt < 4; ++nt)
        acc[mt][nt] = __builtin_amdgcn_mfma_f32_16x16x32_bf16(af[mt], bfr[nt], acc[mt][nt], 0, 0, 0);
  }

  // epilogue: C row = (lane>>4)*4 + reg, col = lane&15   [verified C/D layout]
  const int cr = (lane >> 4) * 4;
  const int cc = lane & 15;
#pragma unroll
  for (int mt = 0; mt < 4; ++mt) {
    size_t r0 = row0 + wm * 64 + mt * 16 + cr;
#pragma unroll
    for (int nt = 0; nt < 4; ++nt) {
      int col = col0 + wn * 64 + nt * 16 + cc;
      float bcol = bias[col];
#pragma unroll
      for (int i = 0; i < 4; ++i) {
        float v = acc[mt][nt][i] + bcol;
        size_t idx = (r0 + i) * N + col;
        if (BF16OUT) ((ushort_t*)Cv)[idx] = f2bf(v);
        else         ((float*)Cv)[idx]    = v;
      }
    }
  }
}

// ---------- kv split-K partials: kvpart[h][s][64][64] = sum over 256 n ----------
// K,V: bf16 [8192][1024] (this batch). grid (16, 32), block 256.
__global__ __launch_bounds__(256) void kv_partial(const ushort_t* __restrict__ Kp,
                                                  const ushort_t* __restrict__ Vp,
                                                  float* __restrict__ kvpart) {
  const int h = blockIdx.x;
  const int s = blockIdx.y;
  const int t = threadIdx.x;
  __shared__ float Kl[64 * 64];
  __shared__ float Vl[64 * 64];

  const int d0 = (t >> 4) * 4;
  const int e0 = (t & 15) * 4;
  float acc[4][4] = {};

  for (int c = 0; c < 4; ++c) {
    const int n0 = s * 256 + c * 64;
    __syncthreads();
#pragma unroll
    for (int r = 0; r < 2; ++r) {
      int row = (t >> 3) + 32 * r;
      int seg = (t & 7) * 8;
      union { shortx8 v; ushort_t hh[8]; } uk, uv;
      uk.v = *(const shortx8*)(Kp + (size_t)(n0 + row) * 1024 + h * 64 + seg);
      uv.v = *(const shortx8*)(Vp + (size_t)(n0 + row) * 1024 + h * 64 + seg);
      floatx4 k03 = { bf2f(uk.hh[0]), bf2f(uk.hh[1]), bf2f(uk.hh[2]), bf2f(uk.hh[3]) };
      floatx4 k47 = { bf2f(uk.hh[4]), bf2f(uk.hh[5]), bf2f(uk.hh[6]), bf2f(uk.hh[7]) };
      floatx4 v03 = { bf2f(uv.hh[0]), bf2f(uv.hh[1]), bf2f(uv.hh[2]), bf2f(uv.hh[3]) };
      floatx4 v47 = { bf2f(uv.hh[4]), bf2f(uv.hh[5]), bf2f(uv.hh[6]), bf2f(uv.hh[7]) };
      *(floatx4*)&Kl[row * 64 + seg]     = k03;
      *(floatx4*)&Kl[row * 64 + seg + 4] = k47;
      *(floatx4*)&Vl[row * 64 + seg]     = v03;
      *(floatx4*)&Vl[row * 64 + seg + 4] = v47;
    }
    __syncthreads();
#pragma unroll 8
    for (int nn = 0; nn < 64; ++nn) {
      floatx4 kk = *(const floatx4*)&Kl[nn * 64 + d0];
      floatx4 vv = *(const floatx4*)&Vl[nn * 64 + e0];
#pragma unroll
      for (int i = 0; i < 4; ++i)
#pragma unroll
        for (int j = 0; j < 4; ++j)
          acc[i][j] += kk[i] * vv[j];
    }
  }
  float* dst = kvpart + ((size_t)h * 32 + s) * 4096;
#pragma unroll
  for (int i = 0; i < 4; ++i) {
    floatx4 row = { acc[i][0], acc[i][1], acc[i][2], acc[i][3] };
    *(floatx4*)&dst[(d0 + i) * 64 + e0] = row;
  }
}

// ---------- reduce partials + row-L2-normalize * gamma -> kvn[h][64][64] fp32 ----------
__global__ __launch_bounds__(256) void kv_norm(const float* __restrict__ kvpart,
                                               const float* __restrict__ gamma,
                                               float* __restrict__ kvn) {
  const int h = blockIdx.x;
  const int t = threadIdx.x;
  const int d  = t >> 2;
  const int e0 = (t & 3) * 16;
  floatx4 v[4] = {};
  for (int s = 0; s < 32; ++s) {
    const float* p = kvpart + ((size_t)h * 32 + s) * 4096 + d * 64 + e0;
#pragma unroll
    for (int q = 0; q < 4; ++q) v[q] += *(const floatx4*)(p + q * 4);
  }
  float ss = 0.f;
#pragma unroll
  for (int q = 0; q < 4; ++q)
    ss += v[q].x * v[q].x + v[q].y * v[q].y + v[q].z * v[q].z + v[q].w * v[q].w;
  ss += __shfl_xor(ss, 1, 64);
  ss += __shfl_xor(ss, 2, 64);
  float sc = gamma[h] * rsqrtf(ss);
  float* dst = kvn + (size_t)h * 4096 + d * 64 + e0;
#pragma unroll
  for (int q = 0; q < 4; ++q) { floatx4 o = v[q] * sc; *(floatx4*)(dst + q * 4) = o; }
}

// ---------- in-place q row-normalize (per (m,h) row of 64) ----------
__global__ __launch_bounds__(256) void qnorm_kernel(ushort_t* __restrict__ Q,
                                                    const float* __restrict__ gamma) {
  const int t = threadIdx.x;
  long g = (long)blockIdx.x * 32 + (t >> 3);   // head-row id
  int h = (int)(g & 15);
  long m = g >> 4;
  ushort_t* p = Q + m * 1024 + h * 64 + (t & 7) * 8;
  union { shortx8 v; ushort_t hh[8]; } u;
  u.v = *(shortx8*)p;
  float f[8];
  float ss = 0.f;
#pragma unroll
  for (int i = 0; i < 8; ++i) { f[i] = bf2f(u.hh[i]); ss += f[i] * f[i]; }
  ss += __shfl_xor(ss, 1, 64);
  ss += __shfl_xor(ss, 2, 64);
  ss += __shfl_xor(ss, 4, 64);
  float sc = gamma[h] * rsqrtf(ss);
#pragma unroll
  for (int i = 0; i < 8; ++i) u.hh[i] = f2bf(f[i] * sc);
  *(shortx8*)p = u.v;
}

// ---------- W2T[o][h*64+d] = sum_e kvn[h][d][e] * Wo[o][h*64+e], bf16 out ----------
// grid (16 h, 16 o-tiles), block 256
__global__ __launch_bounds__(256) void w2_kernel(const float* __restrict__ kvn,
                                                 const float* __restrict__ Wo,
                                                 ushort_t* __restrict__ W2T) {
  const int h  = blockIdx.x;
  const int ot = blockIdx.y;
  const int t  = threadIdx.x;
  __shared__ float kvt[64 * 64];   // [e][d]
  __shared__ float wot[64 * 64];   // [e][o]
#pragma unroll
  for (int p = 0; p < 4; ++p) {
    int r  = p * 16 + (t >> 4);
    int c4 = (t & 15) * 4;
    floatx4 a = *(const floatx4*)&kvn[(size_t)h * 4096 + r * 64 + c4];
    floatx4 b = *(const floatx4*)&Wo[(size_t)(ot * 64 + r) * 1024 + h * 64 + c4];
    kvt[(c4 + 0) * 64 + r] = a.x; kvt[(c4 + 1) * 64 + r] = a.y;
    kvt[(c4 + 2) * 64 + r] = a.z; kvt[(c4 + 3) * 64 + r] = a.w;
    wot[(c4 + 0) * 64 + r] = b.x; wot[(c4 + 1) * 64 + r] = b.y;
    wot[(c4 + 2) * 64 + r] = b.z; wot[(c4 + 3) * 64 + r] = b.w;
  }
  __syncthreads();
  const int d0 = (t >> 4) * 4;
  const int o0 = (t & 15) * 4;
  float acc[4][4] = {};
#pragma unroll 8
  for (int e = 0; e < 64; ++e) {
    floatx4 kk = *(const floatx4*)&kvt[e * 64 + d0];
    floatx4 ww = *(const floatx4*)&wot[e * 64 + o0];
#pragma unroll
    for (int i = 0; i < 4; ++i)
#pragma unroll
      for (int j = 0; j < 4; ++j)
        acc[i][j] += kk[i] * ww[j];
  }
#pragma unroll
  for (int j = 0; j < 4; ++j)
#pragma unroll
    for (int i = 0; i < 4; ++i)
      W2T[(size_t)(ot * 64 + o0 + j) * 1024 + h * 64 + d0 + i] = f2bf(acc[i][j]);
}

// ---------- host orchestration ----------
extern "C" void kernel_launch(void* const* d_in, const int* in_sizes, int n_in,
                              void* d_out, int out_size, void* d_ws, size_t ws_size,
                              hipStream_t stream) {
  const float* Xq = (const float*)d_in[0];
  const float* Xk = (const float*)d_in[1];
  const float* Xv = (const float*)d_in[2];
  const float* Wq = (const float*)d_in[3];
  const float* bq = (const float*)d_in[4];
  const float* Wk = (const float*)d_in[5];
  const float* bk = (const float*)d_in[6];
  const float* Wv = (const float*)d_in[7];
  const float* bv = (const float*)d_in[8];
  const float* Wo = (const float*)d_in[9];
  const float* bo = (const float*)d_in[10];
  const float* gamma = (const float*)d_in[11];
  float* out = (float*)d_out;

  const long BN  = 8192;            // rows per batch
  const long PB  = BN * 1024;       // elements per batch slab

  char* ws = (char*)d_ws;
  auto alloc = [&](size_t bytes) { char* p = ws; ws += (bytes + 255) & ~255ull; return p; };
  ushort_t* XBF = (ushort_t*)alloc(PB * 2);          // reusable X bf16
  ushort_t* QBF = (ushort_t*)alloc(PB * 2);
  ushort_t* KBF = (ushort_t*)alloc(PB * 2);
  ushort_t* VBF = (ushort_t*)alloc(PB * 2);
  ushort_t* WQB = (ushort_t*)alloc(1024 * 1024 * 2);
  ushort_t* WKB = (ushort_t*)alloc(1024 * 1024 * 2);
  ushort_t* WVB = (ushort_t*)alloc(1024 * 1024 * 2);
  float*    KVP = (float*)alloc((size_t)16 * 32 * 4096 * 4);
  float*    KVN = (float*)alloc((size_t)16 * 4096 * 4);
  ushort_t* W2T = (ushort_t*)alloc(1024 * 1024 * 2);

  // weights -> bf16 (once per call)
  cast_f32_bf16<<<512, 256, 0, stream>>>(Wq, WQB, 1024 * 1024);
  cast_f32_bf16<<<512, 256, 0, stream>>>(Wk, WKB, 1024 * 1024);
  cast_f32_bf16<<<512, 256, 0, stream>>>(Wv, WVB, 1024 * 1024);

  dim3 ggrid(64, 8);   // M=8192 / 128, N=1024 / 128
  for (int b = 0; b < 4; ++b) {
    const long off = (long)b * PB;
    // Q projection
    cast_f32_bf16<<<4096, 256, 0, stream>>>(Xq + off, XBF, PB);
    gemm_bt<true><<<ggrid, 256, 0, stream>>>(XBF, WQB, bq, QBF);
    // K projection
    cast_f32_bf16<<<4096, 256, 0, stream>>>(Xk + off, XBF, PB);
    gemm_bt<true><<<ggrid, 256, 0, stream>>>(XBF, WKB, bk, KBF);
    // V projection
    cast_f32_bf16<<<4096, 256, 0, stream>>>(Xv + off, XBF, PB);
    gemm_bt<true><<<ggrid, 256, 0, stream>>>(XBF, WVB, bv, VBF);
    // kv = K^T V per head (split-K partials), then normalize
    kv_partial<<<dim3(16, 32), 256, 0, stream>>>(KBF, VBF, KVP);
    kv_norm<<<16, 256, 0, stream>>>(KVP, gamma, KVN);
    // q normalize in place
    qnorm_kernel<<<4096, 256, 0, stream>>>(QBF, gamma);
    // W2T = kvn (x) Wo  (folds kv_n and output projection together)
    w2_kernel<<<dim3(16, 16), 256, 0, stream>>>(KVN, Wo, W2T);
    // final = q_n @ W2T^T + bo   (fp32 out)
    gemm_bt<false><<<ggrid, 256, 0, stream>>>(QBF, W2T, bo, out + off);
  }
}

// Round 2
// 867.578 us; speedup vs baseline: 1.1585x; 1.1585x over previous
//
#include <hip/hip_runtime.h>
#include <stdint.h>

// ---------- types ----------
typedef unsigned short ushort_t;
typedef __attribute__((ext_vector_type(4))) float  floatx4;
typedef __attribute__((ext_vector_type(8))) short  shortx8;   // 8 bf16 (4 VGPRs)

// ---------- bf16 helpers (raw ushort representation) ----------
__device__ __forceinline__ float bf2f(ushort_t u) {
  union { float f; unsigned int i; } x; x.i = ((unsigned int)u) << 16; return x.f;
}
__device__ __forceinline__ ushort_t f2bf(float f) {
  union { float f; unsigned int i; } x; x.f = f;
  unsigned int r = x.i + 0x7fffu + ((x.i >> 16) & 1u);   // RNE
  return (ushort_t)(r >> 16);
}

// ---------- async global->LDS, 16B per lane ----------
__device__ __forceinline__ void gl_lds16(const ushort_t* g, ushort_t* l) {
  __builtin_amdgcn_global_load_lds(
      (const __attribute__((address_space(1))) void*)g,
      (__attribute__((address_space(3))) void*)l, 16, 0, 0);
}

// ---------- fp32 -> bf16 cast, 8 elems/thread ----------
__global__ __launch_bounds__(256) void cast_f32_bf16(const float* __restrict__ in,
                                                     ushort_t* __restrict__ out, long n) {
  long i = ((long)blockIdx.x * 256 + threadIdx.x) * 8;
  if (i + 8 > n) return;
  floatx4 a = *(const floatx4*)(in + i);
  floatx4 b = *(const floatx4*)(in + i + 4);
  union { shortx8 v; ushort_t h[8]; } u;
  u.h[0] = f2bf(a.x); u.h[1] = f2bf(a.y); u.h[2] = f2bf(a.z); u.h[3] = f2bf(a.w);
  u.h[4] = f2bf(b.x); u.h[5] = f2bf(b.y); u.h[6] = f2bf(b.z); u.h[7] = f2bf(b.w);
  *(shortx8*)(out + i) = u.v;
}

// ---------- m97-style GEMM: C[M][1024] = A[M][1024] * B^T + bias ----------
// A: bf16 [M][K=1024] row-major; B: bf16 [1024][1024] row-major (weights).
// OMODE: 0 = bf16 out, 1 = bf16 out + per-head-row L2 norm * gamma (q-norm fused),
//        2 = fp32 out. PBB: B has a per-batch slab of 1M elems selected by blockIdx.x>>6.
// grid (M/128, 8), block 256 (4 waves in 2x2 of 64x64).
template <int OMODE, bool PBB>
__global__ __launch_bounds__(256, 2) void gemm_bt(const ushort_t* __restrict__ A,
                                                  const ushort_t* __restrict__ B,
                                                  const float* __restrict__ bias,
                                                  const float* __restrict__ gamma,
                                                  void* __restrict__ Cv) {
  constexpr int K = 1024;
  constexpr int N = 1024;
  __shared__ ushort_t As[128 * 32];
  __shared__ ushort_t Bs[128 * 32];

  const int t    = threadIdx.x;
  const int lane = t & 63;
  const int w    = t >> 6;
  const int wm   = w >> 1, wn = w & 1;
  const size_t row0 = (size_t)blockIdx.x * 128;
  const int    col0 = blockIdx.y * 128;
  const size_t boff = PBB ? ((size_t)(blockIdx.x >> 6)) * (size_t)(1024 * 1024) : 0;

  // staging: thread t loads 8 bf16 (16B) at tile row t>>2, col (t&3)*8
  const int sr = t >> 2;
  const int sc = (t & 3) * 8;
  const ushort_t* Ag = A + (row0 + sr) * K + sc;
  const ushort_t* Bg = B + boff + (size_t)(col0 + sr) * K + sc;
  ushort_t* Al = As + t * 8;
  ushort_t* Bl = Bs + t * 8;

  floatx4 acc[4][4] = {};

  const int kg = (lane >> 4) * 8;       // k-group 0,8,16,24
  const int fr = lane & 15;             // fragment row/col within 16

  for (int k0 = 0; k0 < K; k0 += 32) {
    __syncthreads();
    gl_lds16(Ag + k0, Al);
    gl_lds16(Ag + 64 * K + k0, Al + 2048);
    gl_lds16(Bg + k0, Bl);
    gl_lds16(Bg + 64 * K + k0, Bl + 2048);
    __syncthreads();

    shortx8 af[4], bfr[4];
#pragma unroll
    for (int i = 0; i < 4; ++i) {
      af[i]  = *(const shortx8*)&As[(wm * 64 + i * 16 + fr) * 32 + kg];
      bfr[i] = *(const shortx8*)&Bs[(wn * 64 + i * 16 + fr) * 32 + kg];
    }
#pragma unroll
    for (int mt = 0; mt < 4; ++mt)
#pragma unroll
      for (int nt = 0; nt < 4; ++nt)
        acc[mt][nt] = __builtin_amdgcn_mfma_f32_16x16x32_bf16(af[mt], bfr[nt], acc[mt][nt], 0, 0, 0);
  }

  // C/D layout: row = (lane>>4)*4 + reg, col = lane&15  [verified]
  const int cr = (lane >> 4) * 4;
  const int cc = lane & 15;

  // bias add (all modes)
  float bcol[4];
#pragma unroll
  for (int nt = 0; nt < 4; ++nt) bcol[nt] = bias[col0 + wn * 64 + nt * 16 + cc];
#pragma unroll
  for (int mt = 0; mt < 4; ++mt)
#pragma unroll
    for (int nt = 0; nt < 4; ++nt)
#pragma unroll
      for (int i = 0; i < 4; ++i) acc[mt][nt][i] += bcol[nt];

  if (OMODE == 1) {
    // this wave's 64-col strip == one head; row-L2 normalize * gamma[h]
    const int h = blockIdx.y * 2 + wn;
    const float g = gamma[h];
#pragma unroll
    for (int mt = 0; mt < 4; ++mt) {
#pragma unroll
      for (int i = 0; i < 4; ++i) {
        float ss = 0.f;
#pragma unroll
        for (int nt = 0; nt < 4; ++nt) { float v = acc[mt][nt][i]; ss += v * v; }
        ss += __shfl_xor(ss, 1);
        ss += __shfl_xor(ss, 2);
        ss += __shfl_xor(ss, 4);
        ss += __shfl_xor(ss, 8);
        const float sc = g * rsqrtf(ss);
#pragma unroll
        for (int nt = 0; nt < 4; ++nt) acc[mt][nt][i] *= sc;
      }
    }
  }

#pragma unroll
  for (int mt = 0; mt < 4; ++mt) {
    size_t r0 = row0 + wm * 64 + mt * 16 + cr;
#pragma unroll
    for (int nt = 0; nt < 4; ++nt) {
      int col = col0 + wn * 64 + nt * 16 + cc;
#pragma unroll
      for (int i = 0; i < 4; ++i) {
        float v = acc[mt][nt][i];
        size_t idx = (r0 + i) * N + col;
        if (OMODE == 2) ((float*)Cv)[idx]    = v;
        else            ((ushort_t*)Cv)[idx] = f2bf(v);
      }
    }
  }
}

// ---------- kv split-K partials: kvpart[bh][s][64][64] = sum over 256 n ----------
// K,V: bf16 [4*8192][1024]. grid (64, 32) = (b*16+h, s), block 256.
__global__ __launch_bounds__(256) void kv_partial(const ushort_t* __restrict__ Kp,
                                                  const ushort_t* __restrict__ Vp,
                                                  float* __restrict__ kvpart) {
  const int bh = blockIdx.x;
  const int h  = bh & 15;
  const long boff = (long)(bh >> 4) * 8192 * 1024;
  const int s = blockIdx.y;
  const int t = threadIdx.x;
  __shared__ float Kl[64 * 64];
  __shared__ float Vl[64 * 64];

  const int d0 = (t >> 4) * 4;
  const int e0 = (t & 15) * 4;
  float acc[4][4] = {};

  for (int c = 0; c < 4; ++c) {
    const int n0 = s * 256 + c * 64;
    __syncthreads();
#pragma unroll
    for (int r = 0; r < 2; ++r) {
      int row = (t >> 3) + 32 * r;
      int seg = (t & 7) * 8;
      union { shortx8 v; ushort_t hh[8]; } uk, uv;
      uk.v = *(const shortx8*)(Kp + boff + (size_t)(n0 + row) * 1024 + h * 64 + seg);
      uv.v = *(const shortx8*)(Vp + boff + (size_t)(n0 + row) * 1024 + h * 64 + seg);
      floatx4 k03 = { bf2f(uk.hh[0]), bf2f(uk.hh[1]), bf2f(uk.hh[2]), bf2f(uk.hh[3]) };
      floatx4 k47 = { bf2f(uk.hh[4]), bf2f(uk.hh[5]), bf2f(uk.hh[6]), bf2f(uk.hh[7]) };
      floatx4 v03 = { bf2f(uv.hh[0]), bf2f(uv.hh[1]), bf2f(uv.hh[2]), bf2f(uv.hh[3]) };
      floatx4 v47 = { bf2f(uv.hh[4]), bf2f(uv.hh[5]), bf2f(uv.hh[6]), bf2f(uv.hh[7]) };
      *(floatx4*)&Kl[row * 64 + seg]     = k03;
      *(floatx4*)&Kl[row * 64 + seg + 4] = k47;
      *(floatx4*)&Vl[row * 64 + seg]     = v03;
      *(floatx4*)&Vl[row * 64 + seg + 4] = v47;
    }
    __syncthreads();
#pragma unroll 8
    for (int nn = 0; nn < 64; ++nn) {
      floatx4 kk = *(const floatx4*)&Kl[nn * 64 + d0];
      floatx4 vv = *(const floatx4*)&Vl[nn * 64 + e0];
#pragma unroll
      for (int i = 0; i < 4; ++i)
#pragma unroll
        for (int j = 0; j < 4; ++j)
          acc[i][j] += kk[i] * vv[j];
    }
  }
  float* dst = kvpart + ((size_t)bh * 32 + s) * 4096;
#pragma unroll
  for (int i = 0; i < 4; ++i) {
    floatx4 row = { acc[i][0], acc[i][1], acc[i][2], acc[i][3] };
    *(floatx4*)&dst[(d0 + i) * 64 + e0] = row;
  }
}

// ---------- reduce partials + row-L2-normalize * gamma -> kvn[bh][64][64] fp32 ----------
__global__ __launch_bounds__(256) void kv_norm(const float* __restrict__ kvpart,
                                               const float* __restrict__ gamma,
                                               float* __restrict__ kvn) {
  const int bh = blockIdx.x;
  const int t = threadIdx.x;
  const int d  = t >> 2;
  const int e0 = (t & 3) * 16;
  floatx4 v[4] = {};
  for (int s = 0; s < 32; ++s) {
    const float* p = kvpart + ((size_t)bh * 32 + s) * 4096 + d * 64 + e0;
#pragma unroll
    for (int q = 0; q < 4; ++q) v[q] += *(const floatx4*)(p + q * 4);
  }
  float ss = 0.f;
#pragma unroll
  for (int q = 0; q < 4; ++q)
    ss += v[q].x * v[q].x + v[q].y * v[q].y + v[q].z * v[q].z + v[q].w * v[q].w;
  ss += __shfl_xor(ss, 1, 64);
  ss += __shfl_xor(ss, 2, 64);
  float sc = gamma[bh & 15] * rsqrtf(ss);
  float* dst = kvn + (size_t)bh * 4096 + d * 64 + e0;
#pragma unroll
  for (int q = 0; q < 4; ++q) { floatx4 o = v[q] * sc; *(floatx4*)(dst + q * 4) = o; }
}

// ---------- W2T[b][o][h*64+d] = sum_e kvn[bh][d][e] * Wo[o][h*64+e], bf16 out ----------
// grid (64 bh, 16 o-tiles), block 256
__global__ __launch_bounds__(256) void w2_kernel(const float* __restrict__ kvn,
                                                 const float* __restrict__ Wo,
                                                 ushort_t* __restrict__ W2T) {
  const int bh = blockIdx.x;
  const int h  = bh & 15;
  const int ot = blockIdx.y;
  const int t  = threadIdx.x;
  __shared__ float kvt[64 * 64];   // [e][d]
  __shared__ float wot[64 * 64];   // [e][o]
#pragma unroll
  for (int p = 0; p < 4; ++p) {
    int r  = p * 16 + (t >> 4);
    int c4 = (t & 15) * 4;
    floatx4 a = *(const floatx4*)&kvn[(size_t)bh * 4096 + r * 64 + c4];
    floatx4 b = *(const floatx4*)&Wo[(size_t)(ot * 64 + r) * 1024 + h * 64 + c4];
    kvt[(c4 + 0) * 64 + r] = a.x; kvt[(c4 + 1) * 64 + r] = a.y;
    kvt[(c4 + 2) * 64 + r] = a.z; kvt[(c4 + 3) * 64 + r] = a.w;
    wot[(c4 + 0) * 64 + r] = b.x; wot[(c4 + 1) * 64 + r] = b.y;
    wot[(c4 + 2) * 64 + r] = b.z; wot[(c4 + 3) * 64 + r] = b.w;
  }
  __syncthreads();
  const int d0 = (t >> 4) * 4;
  const int o0 = (t & 15) * 4;
  float acc[4][4] = {};
#pragma unroll 8
  for (int e = 0; e < 64; ++e) {
    floatx4 kk = *(const floatx4*)&kvt[e * 64 + d0];
    floatx4 ww = *(const floatx4*)&wot[e * 64 + o0];
#pragma unroll
    for (int i = 0; i < 4; ++i)
#pragma unroll
      for (int j = 0; j < 4; ++j)
        acc[i][j] += kk[i] * ww[j];
  }
  ushort_t* dst = W2T + (size_t)(bh >> 4) * 1024 * 1024;
#pragma unroll
  for (int j = 0; j < 4; ++j)
#pragma unroll
    for (int i = 0; i < 4; ++i)
      dst[(size_t)(ot * 64 + o0 + j) * 1024 + h * 64 + d0 + i] = f2bf(acc[i][j]);
}

// ---------- host orchestration ----------
extern "C" void kernel_launch(void* const* d_in, const int* in_sizes, int n_in,
                              void* d_out, int out_size, void* d_ws, size_t ws_size,
                              hipStream_t stream) {
  const float* Xq = (const float*)d_in[0];
  const float* Xk = (const float*)d_in[1];
  const float* Xv = (const float*)d_in[2];
  const float* Wq = (const float*)d_in[3];
  const float* bq = (const float*)d_in[4];
  const float* Wk = (const float*)d_in[5];
  const float* bk = (const float*)d_in[6];
  const float* Wv = (const float*)d_in[7];
  const float* bv = (const float*)d_in[8];
  const float* Wo = (const float*)d_in[9];
  const float* bo = (const float*)d_in[10];
  const float* gamma = (const float*)d_in[11];
  float* out = (float*)d_out;

  const long M  = 4L * 8192;        // all batches stacked
  const long NE = M * 1024;         // total elements across batches

  char* ws = (char*)d_ws;
  auto alloc = [&](size_t bytes) { char* p = ws; ws += (bytes + 255) & ~255ull; return p; };
  ushort_t* XBF = (ushort_t*)alloc(NE * 2);          // reusable X bf16
  ushort_t* QBF = (ushort_t*)alloc(NE * 2);
  ushort_t* KBF = (ushort_t*)alloc(NE * 2);
  ushort_t* VBF = (ushort_t*)alloc(NE * 2);
  ushort_t* WQB = (ushort_t*)alloc(1024 * 1024 * 2);
  ushort_t* WKB = (ushort_t*)alloc(1024 * 1024 * 2);
  ushort_t* WVB = (ushort_t*)alloc(1024 * 1024 * 2);
  float*    KVP = (float*)alloc((size_t)64 * 32 * 4096 * 4);
  float*    KVN = (float*)alloc((size_t)64 * 4096 * 4);
  ushort_t* W2T = (ushort_t*)alloc((size_t)4 * 1024 * 1024 * 2);

  // weights -> bf16
  cast_f32_bf16<<<512, 256, 0, stream>>>(Wq, WQB, 1024 * 1024);
  cast_f32_bf16<<<512, 256, 0, stream>>>(Wk, WKB, 1024 * 1024);
  cast_f32_bf16<<<512, 256, 0, stream>>>(Wv, WVB, 1024 * 1024);

  dim3 ggrid(256, 8);   // M=32768/128, N=1024/128

  // Q projection + fused q-norm (all batches)
  cast_f32_bf16<<<16384, 256, 0, stream>>>(Xq, XBF, NE);
  gemm_bt<1, false><<<ggrid, 256, 0, stream>>>(XBF, WQB, bq, gamma, QBF);
  // K projection
  cast_f32_bf16<<<16384, 256, 0, stream>>>(Xk, XBF, NE);
  gemm_bt<0, false><<<ggrid, 256, 0, stream>>>(XBF, WKB, bk, nullptr, KBF);
  // V projection
  cast_f32_bf16<<<16384, 256, 0, stream>>>(Xv, XBF, NE);
  gemm_bt<0, false><<<ggrid, 256, 0, stream>>>(XBF, WVB, bv, nullptr, VBF);

  // kv = K^T V per (b,h), split-K partials + normalize
  kv_partial<<<dim3(64, 32), 256, 0, stream>>>(KBF, VBF, KVP);
  kv_norm<<<64, 256, 0, stream>>>(KVP, gamma, KVN);

  // W2T[b] = kvn[b] folded into Wo
  w2_kernel<<<dim3(64, 16), 256, 0, stream>>>(KVN, Wo, W2T);

  // final = q_n @ W2T[b]^T + bo  (fp32 out, per-batch B slab)
  gemm_bt<2, true><<<ggrid, 256, 0, stream>>>(QBF, W2T, bo, nullptr, out);
}